// Round 2
// baseline (410.459 us; speedup 1.0000x reference)
//
#include <hip/hip_runtime.h>

// ImageBuffer: sliding-window gather, restructured as a SCATTER over source
// frames. combined = concat(buffer[16], inputs[128]); out[b][k] = combined[b+1+k].
// For a fixed source frame j (1..143), its consumers are the output frames
// f = b*16+k with b = j-1-k, k in [max(0,j-128), min(15,j-1)]  (up to 16).
// Each thread reads its float4 ONCE and stores it to all consumers —
// guarantees a single HBM read pass (~28 MB) vs 16x amplification in the
// gather form. Writes (402 MB) are mandatory and fully coalesced.

constexpr int BATCH     = 128;
constexpr int KBUF      = 16;
constexpr int FRAME_F32 = 128 * 128 * 3;      // 49152 floats per frame
constexpr int FRAME_F4  = FRAME_F32 / 4;      // 12288 float4 per frame
constexpr int BLOCK     = 256;
constexpr int CHUNKS    = FRAME_F4 / BLOCK;   // 48 chunks per frame

__global__ __launch_bounds__(BLOCK)
void ImageBuffer_86784109183359_kernel(const float4* __restrict__ inputs,
                                       const float4* __restrict__ buffer,
                                       float4* __restrict__ out) {
    const int bid   = blockIdx.x;
    const int j     = 1 + bid / CHUNKS;       // source frame in combined, 1..143
    const int chunk = bid % CHUNKS;
    const int off   = chunk * BLOCK + threadIdx.x;   // float4 index within frame

    // One read per element, total ~28 MB across the grid.
    const float4* __restrict__ src =
        (j < KBUF) ? (buffer + (size_t)j * FRAME_F4)
                   : (inputs + (size_t)(j - KBUF) * FRAME_F4);
    const float4 v = src[off];

    // Consumers of source frame j (bounds are block-uniform -> no divergence).
    const int k_lo = (j - BATCH > 0) ? (j - BATCH) : 0;
    const int k_hi = (j - 1 < KBUF - 1) ? (j - 1) : (KBUF - 1);

    #pragma unroll
    for (int k = 0; k < KBUF; ++k) {
        if (k < k_lo || k > k_hi) continue;   // uniform predicate
        const int b = j - 1 - k;              // batch index
        const size_t f = (size_t)(b * KBUF + k);   // output frame index
        out[f * FRAME_F4 + off] = v;
    }
}

extern "C" void kernel_launch(void* const* d_in, const int* in_sizes, int n_in,
                              void* d_out, int out_size, void* d_ws, size_t ws_size,
                              hipStream_t stream) {
    const float4* inputs = (const float4*)d_in[0];  // [128,128,128,3] fp32
    const float4* buffer = (const float4*)d_in[1];  // [16,128,128,3] fp32
    float4* out = (float4*)d_out;                   // [128,16,128,128,3] fp32

    const int n_src  = BATCH + KBUF - 1;            // frames 1..143 are consumed
    const int grid   = n_src * CHUNKS;              // 143 * 48 = 6864 blocks

    ImageBuffer_86784109183359_kernel<<<grid, BLOCK, 0, stream>>>(inputs, buffer, out);
}